// Round 5
// baseline (25367.090 us; speedup 1.0000x reference)
//
#include <hip/hip_runtime.h>

#define T_LEN 1024
#define B_N   64
#define D_N   256
#define Q_N   128
#define WCOLS 2816      // Wcat: 256 w | 256 pu | 256 pv | 1024 gi | 1024 gh
#define GROW  1792      // exchanged row: 768 (w|pu|pv) + 1024 (gi+gh summed)
#define NT    512       // 8 waves per WG (184 VGPR -> 8 waves/CU fits)
#define NGRP  8         // groups
#define GB    8         // batches per group (every member owns one batch)
#define GWGS  8         // WGs per group (8 WGs x 8 waves = 64 weight waves)

typedef __attribute__((ext_vector_type(8))) short short8;
typedef __attribute__((ext_vector_type(4))) float floatx4;

#define MFMA16(A, B, C) __builtin_amdgcn_mfma_f32_16x16x32_bf16((A), (B), (C), 0, 0, 0)

__device__ __forceinline__ float fsigmoid(float x) { return 1.f / (1.f + __expf(-x)); }
__device__ __forceinline__ float ftanh(float x) {
  float ax = fabsf(x);
  float e = __expf(-2.f * ax);
  float r = (1.f - e) / (1.f + e);
  return (x < 0.f) ? -r : r;
}

// ---- PROVEN exchange primitives (identical to the 18.3ms baseline) ----------
// sc0 sc1 on all exchanged data; agent-scope relaxed atomics for flags.
__device__ __forceinline__ floatx4 ld4_sc(const float* a) {
  floatx4 r;
  asm volatile("global_load_dwordx4 %0, %1, off sc0 sc1" : "=v"(r) : "v"(a) : "memory");
  return r;
}
__device__ __forceinline__ float ld1_sc(const float* a) {
  float r;
  asm volatile("global_load_dword %0, %1, off sc0 sc1" : "=v"(r) : "v"(a) : "memory");
  return r;
}
__device__ __forceinline__ void st1_sc(float* a, float v) {
  asm volatile("global_store_dword %0, %1, off sc0 sc1" :: "v"(a), "v"(v) : "memory");
}
__device__ __forceinline__ void st4_sc(float* a, floatx4 v) {
  asm volatile("global_store_dwordx4 %0, %1, off sc0 sc1" :: "v"(a), "v"(v) : "memory");
}
__device__ __forceinline__ void vm_drain() { asm volatile("s_waitcnt vmcnt(0)" ::: "memory"); }
#define TIE(x) asm volatile("" : "+v"(x))

// 3-term truncation split of A: x = h + m + l + eps, |eps| <~ 2^-24 |x|
struct Split3 { short8 h, m, l; };
__device__ __forceinline__ Split3 split8(const float* x) {
  union U { unsigned u[4]; short8 s; } H, M, L;
#pragma unroll
  for (int i = 0; i < 4; ++i) {
    float x0 = x[2 * i], x1 = x[2 * i + 1];
    unsigned h0 = __float_as_uint(x0) & 0xffff0000u;
    unsigned h1 = __float_as_uint(x1) & 0xffff0000u;
    float r0 = x0 - __uint_as_float(h0);
    float r1 = x1 - __uint_as_float(h1);
    unsigned m0 = __float_as_uint(r0) & 0xffff0000u;
    unsigned m1 = __float_as_uint(r1) & 0xffff0000u;
    float s0 = r0 - __uint_as_float(m0);
    float s1 = r1 - __uint_as_float(m1);
    H.u[i] = (h0 >> 16) | h1;
    M.u[i] = (m0 >> 16) | m1;
    L.u[i] = (__float_as_uint(s0) >> 16) | (__float_as_uint(s1) & 0xffff0000u);
  }
  Split3 r; r.h = H.s; r.m = M.s; r.l = L.s; return r;
}

// 5-product split MFMA: hh, hm, mh, mm, lh  (dropped hl ~2^-17 static weight-l)
__device__ __forceinline__ floatx4 mfma5(floatx4 acc, const Split3& A, short8 Bh, short8 Bm) {
  acc = MFMA16(A.l, Bh, acc);
  acc = MFMA16(A.m, Bm, acc);
  acc = MFMA16(A.m, Bh, acc);
  acc = MFMA16(A.h, Bm, acc);
  acc = MFMA16(A.h, Bh, acc);
  return acc;
}

// ---------------- prep: W -> 2-way bf16 split; vstate=v0; flags=0 ------------
__global__ void prep_kernel(const float* __restrict__ Wpu, const float* __restrict__ Wqu,
                            const float* __restrict__ Wpv, const float* __restrict__ Wih,
                            const float* __restrict__ Whh, const float* __restrict__ v0,
                            unsigned short* __restrict__ Wh, unsigned short* __restrict__ Wm,
                            float* __restrict__ vstate, unsigned* __restrict__ flags) {
  int idx = blockIdx.x * 256 + threadIdx.x;
  const int total = WCOLS * 256;                // 720896
  if (idx < total) {
    int n = idx >> 8, k = idx & 255;
    float w;
    if      (n < 256)  w = Wqu[k * 256 + n];            // w:  (v^T Wqu)_n
    else if (n < 512)  w = Wpu[k * 256 + (n - 256)];    // pu
    else if (n < 768)  w = Wpv[k * 256 + (n - 512)];    // pv
    else if (n < 1792) w = Wih[(n - 768) * 256 + k];    // gi_j = sum_k v[k] Wih[j][k]
    else               w = Whh[(n - 1792) * 256 + k];   // gh_j = sum_k ut[k] Whh[j][k]
    unsigned hb = __float_as_uint(w) & 0xffff0000u;
    float r1 = w - __uint_as_float(hb);
    Wh[idx] = (unsigned short)(hb >> 16);
    Wm[idx] = (unsigned short)((__float_as_uint(r1) & 0xffff0000u) >> 16);
  } else if (idx < total + B_N * 256) {
    int i = idx - total;
    vstate[i] = v0[i];
  } else if (idx < total + B_N * 256 + 2048) {
    flags[idx - total - B_N * 256] = 0u;
  }
}

// ---------------- prep_M: M_b = Q^T Q (256x256 per batch), qs_b = sum_j q_j --
__global__ void prep_M(const float* __restrict__ q, float* __restrict__ Mout,
                       float* __restrict__ qsout) {
  extern __shared__ float qb[];                 // 128 x 257 (pad)
  const int b = blockIdx.x, tid = threadIdx.x;
  for (int j = 0; j < Q_N; ++j)
    qb[j * 257 + tid] = q[((size_t)j * B_N + b) * D_N + tid];
  __syncthreads();
  float s = 0.f;
  for (int j = 0; j < Q_N; ++j) s += qb[j * 257 + tid];
  qsout[b * 256 + tid] = s;
  for (int pe = 0; pe < 16; ++pe) {
    const int e0 = pe * 16;
    float acc[16];
#pragma unroll
    for (int e = 0; e < 16; ++e) acc[e] = 0.f;
    for (int j = 0; j < Q_N; ++j) {
      float qd = qb[j * 257 + tid];
#pragma unroll
      for (int e = 0; e < 16; ++e) acc[e] += qb[j * 257 + e0 + e] * qd;
    }
#pragma unroll
    for (int e = 0; e < 16; ++e)
      Mout[(size_t)b * 65536 + (size_t)(e0 + e) * 256 + tid] = acc[e];
  }
}

// ---------------- group sync: NF parallel flags per (group, kind) ------------
template<int NF>
__device__ __forceinline__ void wait_flags(const unsigned* f, unsigned val) {
  if (threadIdx.x < 64) {
    const unsigned* fp = f + (threadIdx.x & (NF - 1));
    unsigned v = __hip_atomic_load(fp, __ATOMIC_RELAXED, __HIP_MEMORY_SCOPE_AGENT);
    while (__any((int)(v < val))) {
      __builtin_amdgcn_s_sleep(1);
      v = __hip_atomic_load(fp, __ATOMIC_RELAXED, __HIP_MEMORY_SCOPE_AGENT);
    }
  }
  __syncthreads();                   // no acquire fence: data read via sc0sc1
}
__device__ __forceinline__ void signal_flag(unsigned* f, unsigned val) {
  vm_drain();                        // my wave's sc1 stores reached coherence pt
  __syncthreads();                   // all waves drained
  if (threadIdx.x == 0)
    __hip_atomic_store(f, val, __ATOMIC_RELAXED, __HIP_MEMORY_SCOPE_AGENT);
}

// ---------------- main: 64 WGs x 512 thr; 8 groups x 8 WGs; b = g*8+m --------
// Each WG = 8 waves holding 88 weight-cols; member m also owns batch b's
// phase 2. Fan-in per barrier = 8 (was 16). Proven exchange semantics; no
// dependence on XCD placement for correctness OR liveness.
__launch_bounds__(NT, 1)
__global__ void pq_main(const float* __restrict__ p,
                        const float* __restrict__ bih, const float* __restrict__ bhh,
                        const unsigned short* __restrict__ Wh,
                        const unsigned short* __restrict__ Wm,
                        const float* __restrict__ Mmat, const float* __restrict__ qs,
                        float* G, float* vstate, unsigned* flags,
                        float* __restrict__ out) {
  extern __shared__ float Msh[];     // 128KB: cache of M_b rows 0..127
  __shared__ float warr[256];
  __shared__ float2 red2[256];
  __shared__ float scal[2];          // beta, 1/r
  __shared__ float LDSg[8][224];     // scatter staging: [8 rows][96 wpv | 128 g]

  const int tid   = threadIdx.x;
  const int bid   = blockIdx.x;
  const int g     = bid >> 3;            // group 0..7
  const int m     = bid & 7;             // member 0..7 (== owner of batch b)
  const int b     = g * GB + m;
  const int lane  = tid & 63;
  const int widx  = tid >> 6;            // wave 0..7
  const int gw    = m * 8 + widx;        // group-wave 0..63
  const int n1    = gw * 12;             // tile1: 12 cols of [w|pu|pv]
  const int n2    = 768  + gw * 16;      // tile2: gi cols
  const int n3    = 1792 + gw * 16;      // tile3: gh cols (same gate j as tile2)
  const int row   = lane & 15;           // B-fragment col index
  const int arow  = lane & 7;            // A-row: batches 0..7 (rows 8..15 dup)
  const int kb    = lane >> 4;

  unsigned* flagsA = flags + g * 64;       // 8 dwords (group-private line)
  unsigned* flagsB = flags + g * 64 + 32;  // 8 dwords (next line)

  // per-thread phase-2 constants (valid for tid<256 only; guard OOB loads)
  float bI = 0.f, bF = 0.f, bG = 0.f, bO = 0.f, qsd = 0.f, vprev = 0.f;
  if (tid < 256) {
    bI = bih[tid]       + bhh[tid];
    bF = bih[256 + tid] + bhh[256 + tid];
    bG = bih[512 + tid] + bhh[512 + tid];
    bO = bih[768 + tid] + bhh[768 + tid];
    qsd = qs[b * 256 + tid];
    vprev = vstate[(size_t)b * 256 + tid];  // fresh via kernel-boundary flush
  }
  const float* Mb = Mmat + (size_t)b * 65536;

  // ---- cache M_b rows 0..127 in LDS (constant across all steps) ----
  for (int i = tid; i < 128 * 256; i += NT) Msh[i] = Mb[i];

  // ---- register-resident B fragments: 3 tiles x 2 splits x 8 k-steps ----
  short8 Bh1[8], Bm1[8], Bhg[8], Bmg[8], Bh2[8], Bm2[8];
#pragma unroll
  for (int ks = 0; ks < 8; ++ks) {
    int ko = ks * 32 + kb * 8;
    int c1 = (n1 + row) * 256 + ko;      // rows 12..15 overshoot: unused in scatter
    int c2 = (n2 + row) * 256 + ko;
    int c3 = (n3 + row) * 256 + ko;
    Bh1[ks] = *(const short8*)&Wh[c1];  Bm1[ks] = *(const short8*)&Wm[c1];
    Bhg[ks] = *(const short8*)&Wh[c2];  Bmg[ks] = *(const short8*)&Wm[c2];
    Bh2[ks] = *(const short8*)&Wh[c3];  Bm2[ks] = *(const short8*)&Wm[c3];
  }

  // ---- gh tile for t=0 from p[0] (plain cached loads) ----
  floatx4 acc2 = {0.f, 0.f, 0.f, 0.f};
  {
    const float* pb = p + ((size_t)0 * B_N + g * GB) * D_N;
#pragma unroll
    for (int ks = 0; ks < 8; ++ks) {
      float xa[8];
      const float* pr = pb + arow * D_N + ks * 32 + kb * 8;
      *(float4*)&xa[0] = *(const float4*)pr;
      *(float4*)&xa[4] = *(const float4*)(pr + 4);
      Split3 A = split8(xa);
      acc2 = mfma5(acc2, A, Bh2[ks], Bm2[ks]);
    }
  }

  float hout = 0.f;
  const float* vb = vstate + (size_t)(g * GB) * 256;

  for (int t = 0; t < T_LEN; ++t) {
    // ---- wait all v_t stored (8 owners); issue v-frag loads, ONE drain ----
    wait_flags<GB>(flagsB, (unsigned)t);

    floatx4 va[8][2];
#pragma unroll
    for (int ks = 0; ks < 8; ++ks) {
      const float* vr = vb + arow * 256 + ks * 32 + kb * 8;
      va[ks][0] = ld4_sc(vr);
      va[ks][1] = ld4_sc(vr + 4);
    }
    vm_drain();
#pragma unroll
    for (int ks = 0; ks < 8; ++ks) { TIE(va[ks][0]); TIE(va[ks][1]); }

    floatx4 acc1 = {0.f, 0.f, 0.f, 0.f}, accg = {0.f, 0.f, 0.f, 0.f};
#pragma unroll
    for (int ks = 0; ks < 8; ++ks) {
      float xa[8];
      *(floatx4*)&xa[0] = va[ks][0];
      *(floatx4*)&xa[4] = va[ks][1];
      Split3 A = split8(xa);
      acc1 = mfma5(acc1, A, Bh1[ks], Bm1[ks]);
      accg = mfma5(accg, A, Bhg[ks], Bmg[ks]);
    }

    // ---- stage my G slice (8 waves) to LDS, store COALESCED dwordx4 ----
    {
      int col = lane & 15, r0q = lane >> 4;
      if (r0q < 2) {                       // rows 0..7 only (8..15 are dups)
#pragma unroll
        for (int r = 0; r < 4; ++r) {
          int rr = r0q * 4 + r;
          if (col < 12) LDSg[rr][widx * 12 + col] = acc1[r];
          LDSg[rr][96 + widx * 16 + col] = accg[r] + acc2[r];   // gi+gh
        }
      }
    }
    __syncthreads();
    if (tid < 192) {                       // seg1: [8 rows][96 cols] w|pu|pv
      int flat = tid * 4, r = flat / 96, c = flat % 96;
      st4_sc(&G[(size_t)(g * GB + r) * GROW + m * 96 + c],
             *(const floatx4*)&LDSg[r][c]);
    } else if (tid < 448) {                // seg2: [8 rows][128 cols] gates
      int flat = (tid - 192) * 4, r = flat / 128, c = flat % 128;
      st4_sc(&G[(size_t)(g * GB + r) * GROW + 768 + m * 128 + c],
             *(const floatx4*)&LDSg[r][96 + c]);
    }
    signal_flag(&flagsA[m], (unsigned)(t + 1));

    // ---- next-step gh tile: off the critical path ----
    floatx4 acc2n = {0.f, 0.f, 0.f, 0.f};
    if (t + 1 < T_LEN) {
      const float* pb = p + ((size_t)(t + 1) * B_N + g * GB) * D_N;
#pragma unroll
      for (int ks = 0; ks < 8; ++ks) {
        float xa[8];
        const float* pr = pb + arow * D_N + ks * 32 + kb * 8;
        *(float4*)&xa[0] = *(const float4*)pr;
        *(float4*)&xa[4] = *(const float4*)(pr + 4);
        Split3 A = split8(xa);
        acc2n = mfma5(acc2n, A, Bh2[ks], Bm2[ks]);
      }
    }

    // ---- phase 2: every WG owns batch b; threads 0..255 do the work ----
    wait_flags<GWGS>(flagsA, (unsigned)(t + 1));
    {
      const float* gr = G + (size_t)b * GROW;
      float w_ = 0.f, pu = 0.f, pv = 0.f, g0 = 0.f, g1 = 0.f, g2 = 0.f, g3 = 0.f;
      float utd = 0.f;
      if (tid < 256) {
        utd = p[((size_t)t * B_N + b) * D_N + tid];   // L2-hot (acc2 touched it)
        w_ = ld1_sc(gr + tid);
        pu = ld1_sc(gr + 256 + tid);
        pv = ld1_sc(gr + 512 + tid);
        g0 = ld1_sc(gr + 768 + tid);
        g1 = ld1_sc(gr + 1024 + tid);
        g2 = ld1_sc(gr + 1280 + tid);
        g3 = ld1_sc(gr + 1536 + tid);
      }
      vm_drain();
      TIE(w_); TIE(pu); TIE(pv); TIE(g0); TIE(g1); TIE(g2); TIE(g3);

      if (tid < 256) {
        warr[tid] = w_;
        red2[tid] = make_float2(pu * utd + pv * vprev, qsd * w_);
      }
      __syncthreads();
      if (tid < 64) {
        float2 s = red2[tid];
        float2 s1 = red2[tid + 64], s2 = red2[tid + 128], s3 = red2[tid + 192];
        s.x += s1.x + s2.x + s3.x;  s.y += s1.y + s2.y + s3.y;
#pragma unroll
        for (int off = 1; off < 64; off <<= 1) {
          s.x += __shfl_xor(s.x, off);
          s.y += __shfl_xor(s.y, off);
        }
        if (tid == 0) {
          float beta = s.x;
          float r = s.y + 128.f * beta;      // r = qs.w + Q*beta
          scal[0] = beta;
          scal[1] = 1.f / r;
        }
      }
      __syncthreads();

      // md = (M_b w)[tid]: rows 0..127 from LDS, 128..255 from L2
      if (tid < 256) {
        float md0 = 0.f, md1 = 0.f, md2 = 0.f, md3 = 0.f;
#pragma unroll 8
        for (int e = 0; e < 128; e += 4) {
          md0 += Msh[(e + 0) * 256 + tid] * warr[e + 0];
          md1 += Msh[(e + 1) * 256 + tid] * warr[e + 1];
          md2 += Msh[(e + 2) * 256 + tid] * warr[e + 2];
          md3 += Msh[(e + 3) * 256 + tid] * warr[e + 3];
        }
#pragma unroll 8
        for (int e = 128; e < 256; e += 4) {
          md0 += Mb[(size_t)(e + 0) * 256 + tid] * warr[e + 0];
          md1 += Mb[(size_t)(e + 1) * 256 + tid] * warr[e + 1];
          md2 += Mb[(size_t)(e + 2) * 256 + tid] * warr[e + 2];
          md3 += Mb[(size_t)(e + 3) * 256 + tid] * warr[e + 3];
        }
        float md = (md0 + md1) + (md2 + md3);

        float beta = scal[0], invr = scal[1];
        float cctx = (md + beta * qsd) * invr;
        float cn = fsigmoid(g1 + bF) * cctx + fsigmoid(g0 + bI) * ftanh(g2 + bG);
        hout = fsigmoid(g3 + bO) * ftanh(cn);
        st1_sc(&vstate[(size_t)b * 256 + tid], hout);
        vprev = hout;
      }
      signal_flag(&flagsB[m], (unsigned)(t + 1));
    }
    acc2 = acc2n;
  }

  if (tid < 256) out[b * 256 + tid] = hout;
}

extern "C" void kernel_launch(void* const* d_in, const int* in_sizes, int n_in,
                              void* d_out, int out_size, void* d_ws, size_t ws_size,
                              hipStream_t stream) {
  const float* p   = (const float*)d_in[0];
  const float* q   = (const float*)d_in[1];
  const float* v0  = (const float*)d_in[2];
  const float* Wpu = (const float*)d_in[3];
  const float* Wqu = (const float*)d_in[4];
  const float* Wpv = (const float*)d_in[5];
  const float* Wih = (const float*)d_in[6];
  const float* Whh = (const float*)d_in[7];
  const float* bih = (const float*)d_in[8];
  const float* bhh = (const float*)d_in[9];
  float* out = (float*)d_out;

  char* ws = (char*)d_ws;
  unsigned short* Wh = (unsigned short*)(ws + 0x000000);   // 1,441,792 B
  unsigned short* Wm = (unsigned short*)(ws + 0x160000);   // 1,441,792 B
  float*    G      = (float*)(ws + 0x2C0000);              //   458,752 B
  float*    vstate = (float*)(ws + 0x330000);              //    65,536 B
  unsigned* flags  = (unsigned*)(ws + 0x340000);           //     8,192 B
  float*    qs     = (float*)(ws + 0x350000);              //    65,536 B
  float*    Mmat   = (float*)(ws + 0x360000);              // 16,777,216 B
  if (ws_size < 0x1360000u) return;

  const int prep_items = WCOLS * 256 + B_N * 256 + 2048;   // 739,328
  prep_kernel<<<(prep_items + 255) / 256, 256, 0, stream>>>(
      Wpu, Wqu, Wpv, Wih, Whh, v0, Wh, Wm, vstate, flags);

  const size_t m_smem = 128 * 257 * sizeof(float);          // 131,584 B
  hipFuncSetAttribute(reinterpret_cast<const void*>(prep_M),
                      hipFuncAttributeMaxDynamicSharedMemorySize, (int)m_smem);
  prep_M<<<64, 256, m_smem, stream>>>(q, Mmat, qs);

  // pq_main: 128KB dynamic LDS for the per-WG M cache.
  const size_t main_smem = 128 * 256 * sizeof(float);       // 131,072 B
  hipFuncSetAttribute(reinterpret_cast<const void*>(pq_main),
                      hipFuncAttributeMaxDynamicSharedMemorySize, (int)main_smem);

  // 64 WGs = 8 groups x 8 members (512 threads each).
  pq_main<<<NGRP * GWGS, NT, main_smem, stream>>>(p, bih, bhh, Wh, Wm, Mmat, qs,
                                                  G, vstate, flags, out);
}

// Round 6
// 16212.282 us; speedup vs baseline: 1.5647x; 1.5647x over previous
//
#include <hip/hip_runtime.h>

#define T_LEN 1024
#define B_N   64
#define D_N   256
#define Q_N   128
#define WCOLS 2560      // Wcat: 256 pu | 256 pv | 1024 gi | 1024 gh  (w cols deleted)
#define GROW  1536      // exchanged row: 512 (pu|pv) + 1024 (gi+gh summed)
#define NT    256
#define NGRP  8         // groups
#define GB    8         // batches per group (owners = members 0..7)
#define GWGS  16        // WGs per group (64 weight waves)

typedef __attribute__((ext_vector_type(8))) short short8;
typedef __attribute__((ext_vector_type(4))) float floatx4;

#define MFMA16(A, B, C) __builtin_amdgcn_mfma_f32_16x16x32_bf16((A), (B), (C), 0, 0, 0)

__device__ __forceinline__ float fsigmoid(float x) { return 1.f / (1.f + __expf(-x)); }
__device__ __forceinline__ float ftanh(float x) {
  float ax = fabsf(x);
  float e = __expf(-2.f * ax);
  float r = (1.f - e) / (1.f + e);
  return (x < 0.f) ? -r : r;
}

// ---- PROVEN exchange primitives (identical to the 18.3ms baseline) ----------
__device__ __forceinline__ floatx4 ld4_sc(const float* a) {
  floatx4 r;
  asm volatile("global_load_dwordx4 %0, %1, off sc0 sc1" : "=v"(r) : "v"(a) : "memory");
  return r;
}
__device__ __forceinline__ float ld1_sc(const float* a) {
  float r;
  asm volatile("global_load_dword %0, %1, off sc0 sc1" : "=v"(r) : "v"(a) : "memory");
  return r;
}
__device__ __forceinline__ void st1_sc(float* a, float v) {
  asm volatile("global_store_dword %0, %1, off sc0 sc1" :: "v"(a), "v"(v) : "memory");
}
__device__ __forceinline__ void st4_sc(float* a, floatx4 v) {
  asm volatile("global_store_dwordx4 %0, %1, off sc0 sc1" :: "v"(a), "v"(v) : "memory");
}
__device__ __forceinline__ void vm_drain() { asm volatile("s_waitcnt vmcnt(0)" ::: "memory"); }
#define TIE(x) asm volatile("" : "+v"(x))

// 3-term truncation split of A: x = h + m + l + eps
struct Split3 { short8 h, m, l; };
__device__ __forceinline__ Split3 split8(const float* x) {
  union U { unsigned u[4]; short8 s; } H, M, L;
#pragma unroll
  for (int i = 0; i < 4; ++i) {
    float x0 = x[2 * i], x1 = x[2 * i + 1];
    unsigned h0 = __float_as_uint(x0) & 0xffff0000u;
    unsigned h1 = __float_as_uint(x1) & 0xffff0000u;
    float r0 = x0 - __uint_as_float(h0);
    float r1 = x1 - __uint_as_float(h1);
    unsigned m0 = __float_as_uint(r0) & 0xffff0000u;
    unsigned m1 = __float_as_uint(r1) & 0xffff0000u;
    float s0 = r0 - __uint_as_float(m0);
    float s1 = r1 - __uint_as_float(m1);
    H.u[i] = (h0 >> 16) | h1;
    M.u[i] = (m0 >> 16) | m1;
    L.u[i] = (__float_as_uint(s0) >> 16) | (__float_as_uint(s1) & 0xffff0000u);
  }
  Split3 r; r.h = H.s; r.m = M.s; r.l = L.s; return r;
}

// 5-product split MFMA: hh, hm, mh, mm, lh
__device__ __forceinline__ floatx4 mfma5(floatx4 acc, const Split3& A, short8 Bh, short8 Bm) {
  acc = MFMA16(A.l, Bh, acc);
  acc = MFMA16(A.m, Bm, acc);
  acc = MFMA16(A.m, Bh, acc);
  acc = MFMA16(A.h, Bm, acc);
  acc = MFMA16(A.h, Bh, acc);
  return acc;
}

// ---------------- prep: W -> 2-way bf16 split; WquT; vstate=v0; flags=0 ------
__global__ void prep_kernel(const float* __restrict__ Wpu, const float* __restrict__ Wqu,
                            const float* __restrict__ Wpv, const float* __restrict__ Wih,
                            const float* __restrict__ Whh, const float* __restrict__ v0,
                            unsigned short* __restrict__ Wh, unsigned short* __restrict__ Wm,
                            float* __restrict__ WquT,
                            float* __restrict__ vstate, unsigned* __restrict__ flags) {
  int idx = blockIdx.x * 256 + threadIdx.x;
  const int total = WCOLS * 256;                // 655360
  if (idx < total) {
    int n = idx >> 8, k = idx & 255;
    float w;
    if      (n < 256)  w = Wpu[k * 256 + n];            // pu_n = sum_k v_k Wpu[k][n]
    else if (n < 512)  w = Wpv[k * 256 + (n - 256)];    // pv
    else if (n < 1536) w = Wih[(n - 512) * 256 + k];    // gi_j = sum_k v[k] Wih[j][k]
    else               w = Whh[(n - 1536) * 256 + k];   // gh_j = sum_k ut[k] Whh[j][k]
    unsigned hb = __float_as_uint(w) & 0xffff0000u;
    float r1 = w - __uint_as_float(hb);
    Wh[idx] = (unsigned short)(hb >> 16);
    Wm[idx] = (unsigned short)((__float_as_uint(r1) & 0xffff0000u) >> 16);
  } else if (idx < total + 65536) {
    int i = idx - total, n = i >> 8, k = i & 255;
    WquT[n * 256 + k] = Wqu[k * 256 + n];               // WquT[n][k] = Wqu[k][n]
  } else if (idx < total + 65536 + B_N * 256) {
    int i = idx - total - 65536;
    vstate[i] = v0[i];
  } else if (idx < total + 65536 + B_N * 256 + 2048) {
    flags[idx - total - 65536 - B_N * 256] = 0u;
  }
}

// ---------------- prep_qz: qs_b = sum_j q_j ; z_b = Wqu @ qs_b ---------------
__global__ void prep_qz(const float* __restrict__ q, const float* __restrict__ WquT,
                        float* __restrict__ qsout, float* __restrict__ zbout) {
  __shared__ float qsh[256];
  const int b = blockIdx.x, tid = threadIdx.x;
  float s = 0.f;
  for (int j = 0; j < Q_N; ++j) s += q[((size_t)j * B_N + b) * D_N + tid];
  qsout[b * 256 + tid] = s;
  qsh[tid] = s;
  __syncthreads();
  float z = 0.f;
  for (int n = 0; n < 256; ++n) z += WquT[n * 256 + tid] * qsh[n];
  zbout[b * 256 + tid] = z;                     // z_b[k] = sum_n Wqu[k][n] qs_n
}

// ---------------- prep_K: K_b = Q^T (Q Wqu^T), bf16 2-way split --------------
// K_b[i][k] = sum_n M_b[i][n] Wqu[k][n]; md = K_b v. Block = (batch, i-chunk of 64).
__global__ void prep_K(const float* __restrict__ q, const float* __restrict__ WquT,
                       unsigned short* __restrict__ KbH, unsigned short* __restrict__ KbM) {
  extern __shared__ float qb[];                 // 128 x 257 (pad)
  const int b = blockIdx.x >> 2, ic = blockIdx.x & 3, tid = threadIdx.x;
  for (int j = 0; j < Q_N; ++j)
    qb[j * 257 + tid] = q[((size_t)j * B_N + b) * D_N + tid];
  __syncthreads();
  float Kacc[64];
#pragma unroll
  for (int i = 0; i < 64; ++i) Kacc[i] = 0.f;
  const int i0 = ic * 64;
  for (int qc = 0; qc < 16; ++qc) {             // chunks of 8 q-rows
    float Pq[8];
#pragma unroll
    for (int qq = 0; qq < 8; ++qq) Pq[qq] = 0.f;
    for (int n = 0; n < 256; ++n) {             // P[q][k=tid] = sum_n Q[q][n] WquT[n][k]
      float wv = WquT[n * 256 + tid];
#pragma unroll
      for (int qq = 0; qq < 8; ++qq) Pq[qq] += qb[(qc * 8 + qq) * 257 + n] * wv;
    }
#pragma unroll
    for (int i = 0; i < 64; ++i) {              // K[i][k] += sum_q Q[q][i] P[q][k]
      float a = 0.f;
#pragma unroll
      for (int qq = 0; qq < 8; ++qq) a += qb[(qc * 8 + qq) * 257 + i0 + i] * Pq[qq];
      Kacc[i] += a;
    }
  }
#pragma unroll
  for (int i = 0; i < 64; ++i) {
    float x = Kacc[i];
    unsigned hb = __float_as_uint(x) & 0xffff0000u;
    float r1 = x - __uint_as_float(hb);
    size_t o = ((size_t)b * 256 + i0 + i) * 256 + tid;
    KbH[o] = (unsigned short)(hb >> 16);
    KbM[o] = (unsigned short)((__float_as_uint(r1) & 0xffff0000u) >> 16);
  }
}

// ---------------- group sync: NF parallel flags per (group, kind) ------------
template<int NF>
__device__ __forceinline__ void wait_flags(const unsigned* f, unsigned val) {
  if (threadIdx.x < 64) {
    const unsigned* fp = f + (threadIdx.x & (NF - 1));
    unsigned v = __hip_atomic_load(fp, __ATOMIC_RELAXED, __HIP_MEMORY_SCOPE_AGENT);
    while (__any((int)(v < val))) {
      __builtin_amdgcn_s_sleep(1);
      v = __hip_atomic_load(fp, __ATOMIC_RELAXED, __HIP_MEMORY_SCOPE_AGENT);
    }
  }
  __syncthreads();
}
__device__ __forceinline__ void signal_flag(unsigned* f, unsigned val) {
  vm_drain();
  __syncthreads();
  if (threadIdx.x == 0)
    __hip_atomic_store(f, val, __ATOMIC_RELAXED, __HIP_MEMORY_SCOPE_AGENT);
}

// ---------------- main: 128 WGs x 256 thr; 8 groups x 16 members -------------
// Owners (m<8): gi+gh tiles + md = K_b v via MFMA (off critical path) + phase 2.
// Non-owners (m>=8): pu|pv tile + gi+gh tiles. w fully eliminated by algebra:
//   md = (M Wqu^T) v = K_b v ;  r = v.z_b + 128*beta.
__launch_bounds__(NT, 1)
__global__ void pq_main(const float* __restrict__ p,
                        const float* __restrict__ bih, const float* __restrict__ bhh,
                        const unsigned short* __restrict__ Wh,
                        const unsigned short* __restrict__ Wm,
                        const unsigned short* __restrict__ KbH,
                        const unsigned short* __restrict__ KbM,
                        const float* __restrict__ qs, const float* __restrict__ zb,
                        float* G, float* vstate, unsigned* flags,
                        float* __restrict__ out) {
  __shared__ float2 red2[256];
  __shared__ float scal[2];          // beta, 1/r
  __shared__ float mdl[256];         // owner: md output routed via LDS
  __shared__ float LDSg[8][128];     // scatter staging

  const int tid   = threadIdx.x;
  const int bid   = blockIdx.x;
  const int g     = bid & 7;             // group
  const int m     = bid >> 3;            // member 0..15
  const bool owner = (m < GB);
  const int b     = g * GB + (m & 7);
  const int lane  = tid & 63;
  const int widx  = tid >> 6;            // wave 0..3
  const int gwave = m * 4 + widx;        // 0..63: gate tile index (all members)
  const int n2    = 512  + gwave * 16;   // gi cols
  const int n3    = 1536 + gwave * 16;   // gh cols
  const int row   = lane & 15;
  const int arow  = lane & 7;            // A-row: batches 0..7 (rows 8..15 dup)
  const int kb    = lane >> 4;

  unsigned* flagsA = flags + g * 64;       // 16 dwords
  unsigned* flagsB = flags + g * 64 + 32;  // 8 dwords

  const float bI = bih[tid]       + bhh[tid];
  const float bF = bih[256 + tid] + bhh[256 + tid];
  const float bG = bih[512 + tid] + bhh[512 + tid];
  const float bO = bih[768 + tid] + bhh[768 + tid];
  const float qsd = qs[b * 256 + tid];
  const float zbd = zb[b * 256 + tid];
  float vprev = vstate[(size_t)b * 256 + tid];

  // ---- register-resident B fragments ----
  short8 Bhg[8], Bmg[8], Bh2[8], Bm2[8], Bh1[8], Bm1[8];
#pragma unroll
  for (int ks = 0; ks < 8; ++ks) {
    int ko = ks * 32 + kb * 8;
    int c2 = (n2 + row) * 256 + ko;
    int c3 = (n3 + row) * 256 + ko;
    Bhg[ks] = *(const short8*)&Wh[c2];  Bmg[ks] = *(const short8*)&Wm[c2];
    Bh2[ks] = *(const short8*)&Wh[c3];  Bm2[ks] = *(const short8*)&Wm[c3];
  }
  if (!owner) {
    const int n1 = ((m - 8) * 4 + widx) * 16;   // pu|pv cols, 16 per wave
#pragma unroll
    for (int ks = 0; ks < 8; ++ks) {
      int ko = ks * 32 + kb * 8;
      int c1 = (n1 + row) * 256 + ko;
      Bh1[ks] = *(const short8*)&Wh[c1];  Bm1[ks] = *(const short8*)&Wm[c1];
    }
  }

  // ---- gh tile for t=0 from p[0] ----
  floatx4 acc2 = {0.f, 0.f, 0.f, 0.f};
  {
    const float* pb = p + ((size_t)0 * B_N + g * GB) * D_N;
#pragma unroll
    for (int ks = 0; ks < 8; ++ks) {
      float xa[8];
      const float* pr = pb + arow * D_N + ks * 32 + kb * 8;
      *(float4*)&xa[0] = *(const float4*)pr;
      *(float4*)&xa[4] = *(const float4*)(pr + 4);
      Split3 A = split8(xa);
      acc2 = mfma5(acc2, A, Bh2[ks], Bm2[ks]);
    }
  }

  float hout = 0.f;
  const float* vb = vstate + (size_t)(g * GB) * 256;

  for (int t = 0; t < T_LEN; ++t) {
    // ---- wait all v_t stored; issue v-frag loads, ONE drain ----
    wait_flags<GB>(flagsB, (unsigned)t);

    floatx4 va[8][2];
#pragma unroll
    for (int ks = 0; ks < 8; ++ks) {
      const float* vr = vb + arow * 256 + ks * 32 + kb * 8;
      va[ks][0] = ld4_sc(vr);
      va[ks][1] = ld4_sc(vr + 4);
    }
    vm_drain();
#pragma unroll
    for (int ks = 0; ks < 8; ++ks) { TIE(va[ks][0]); TIE(va[ks][1]); }

    floatx4 acc1 = {0.f, 0.f, 0.f, 0.f}, accg = {0.f, 0.f, 0.f, 0.f};
#pragma unroll
    for (int ks = 0; ks < 8; ++ks) {
      float xa[8];
      *(floatx4*)&xa[0] = va[ks][0];
      *(floatx4*)&xa[4] = va[ks][1];
      Split3 A = split8(xa);
      accg = mfma5(accg, A, Bhg[ks], Bmg[ks]);
      if (!owner) acc1 = mfma5(acc1, A, Bh1[ks], Bm1[ks]);
    }

    // ---- stage G slice to LDS, store coalesced dwordx4 (sc0 sc1) ----
    {
      int col = lane & 15, r0q = lane >> 4;
      if (r0q < 2) {                       // rows 0..7 (8..15 are dups)
#pragma unroll
        for (int r = 0; r < 4; ++r) {
          int rr = r0q * 4 + r;
          if (owner) {
            LDSg[rr][widx * 16 + col] = accg[r] + acc2[r];            // gates
          } else {
            LDSg[rr][widx * 16 + col] = acc1[r];                      // pu|pv
            LDSg[rr][64 + widx * 16 + col] = accg[r] + acc2[r];       // gates
          }
        }
      }
    }
    __syncthreads();
    if (owner) {
      if (tid < 128) {
        int r = tid >> 4, c = (tid & 15) * 4;
        st4_sc(&G[(size_t)(g * GB + r) * GROW + 512 + m * 64 + c],
               *(const floatx4*)&LDSg[r][c]);
      }
    } else {
      if (tid < 128) {
        int r = tid >> 4, c = (tid & 15) * 4;
        st4_sc(&G[(size_t)(g * GB + r) * GROW + (m - 8) * 64 + c],
               *(const floatx4*)&LDSg[r][c]);
      } else {
        int t2 = tid - 128, r = t2 >> 4, c = (t2 & 15) * 4;
        st4_sc(&G[(size_t)(g * GB + r) * GROW + 512 + m * 64 + c],
               *(const floatx4*)&LDSg[r][64 + c]);
      }
    }
    signal_flag(&flagsA[m], (unsigned)(t + 1));

    // ---- owner: md = K_b v via MFMA (off critical path; reuses va) ----
    if (owner) {
      floatx4 md0 = {0.f,0.f,0.f,0.f}, md1 = {0.f,0.f,0.f,0.f};
      floatx4 md2 = {0.f,0.f,0.f,0.f}, md3 = {0.f,0.f,0.f,0.f};
      const unsigned short* KH = KbH + ((size_t)b * 256 + widx * 64) * 256;
      const unsigned short* KM = KbM + ((size_t)b * 256 + widx * 64) * 256;
#pragma unroll
      for (int ks = 0; ks < 8; ++ks) {
        float xa[8];
        *(floatx4*)&xa[0] = va[ks][0];
        *(floatx4*)&xa[4] = va[ks][1];
        Split3 A = split8(xa);
        int ko = ks * 32 + kb * 8;
        md0 = mfma5(md0, A, *(const short8*)&KH[(      row) * 256 + ko],
                            *(const short8*)&KM[(      row) * 256 + ko]);
        md1 = mfma5(md1, A, *(const short8*)&KH[(16  + row) * 256 + ko],
                            *(const short8*)&KM[(16  + row) * 256 + ko]);
        md2 = mfma5(md2, A, *(const short8*)&KH[(32  + row) * 256 + ko],
                            *(const short8*)&KM[(32  + row) * 256 + ko]);
        md3 = mfma5(md3, A, *(const short8*)&KH[(48  + row) * 256 + ko],
                            *(const short8*)&KM[(48  + row) * 256 + ko]);
      }
      // C layout: row=(lane>>4)*4+r, col=lane&15. Row m carries v_b.
      if ((lane >> 4) == (m >> 2)) {
        int r = m & 3, c = lane & 15;
        mdl[widx * 64 +  0 + c] = md0[r];
        mdl[widx * 64 + 16 + c] = md1[r];
        mdl[widx * 64 + 32 + c] = md2[r];
        mdl[widx * 64 + 48 + c] = md3[r];
      }
    }

    // ---- next-step gh tile: off the critical path ----
    floatx4 acc2n = {0.f, 0.f, 0.f, 0.f};
    if (t + 1 < T_LEN) {
      const float* pb = p + ((size_t)(t + 1) * B_N + g * GB) * D_N;
#pragma unroll
      for (int ks = 0; ks < 8; ++ks) {
        float xa[8];
        const float* pr = pb + arow * D_N + ks * 32 + kb * 8;
        *(float4*)&xa[0] = *(const float4*)pr;
        *(float4*)&xa[4] = *(const float4*)(pr + 4);
        Split3 A = split8(xa);
        acc2n = mfma5(acc2n, A, Bh2[ks], Bm2[ks]);
      }
    }

    // ---- phase 2 (owners only) ----
    if (owner) {
      wait_flags<GWGS>(flagsA, (unsigned)(t + 1));
      const float* gr = G + (size_t)b * GROW;
      float utd = p[((size_t)t * B_N + b) * D_N + tid];
      float pu = ld1_sc(gr + tid);
      float pv = ld1_sc(gr + 256 + tid);
      float g0 = ld1_sc(gr + 512 + tid);
      float g1 = ld1_sc(gr + 768 + tid);
      float g2 = ld1_sc(gr + 1024 + tid);
      float g3 = ld1_sc(gr + 1280 + tid);
      vm_drain();
      TIE(pu); TIE(pv); TIE(g0); TIE(g1); TIE(g2); TIE(g3);

      red2[tid] = make_float2(pu * utd + pv * vprev, vprev * zbd);
      __syncthreads();
      if (tid < 64) {
        float2 s = red2[tid];
        float2 s1 = red2[tid + 64], s2 = red2[tid + 128], s3 = red2[tid + 192];
        s.x += s1.x + s2.x + s3.x;  s.y += s1.y + s2.y + s3.y;
#pragma unroll
        for (int off = 1; off < 64; off <<= 1) {
          s.x += __shfl_xor(s.x, off);
          s.y += __shfl_xor(s.y, off);
        }
        if (tid == 0) {
          float beta = s.x;
          float r = s.y + 128.f * beta;      // r = v.z_b + Q*beta
          scal[0] = beta;
          scal[1] = 1.f / r;
        }
      }
      __syncthreads();

      float beta = scal[0], invr = scal[1];
      float cctx = (mdl[tid] + beta * qsd) * invr;
      float cn = fsigmoid(g1 + bF) * cctx + fsigmoid(g0 + bI) * ftanh(g2 + bG);
      hout = fsigmoid(g3 + bO) * ftanh(cn);
      st1_sc(&vstate[(size_t)b * 256 + tid], hout);
      vprev = hout;
      signal_flag(&flagsB[m], (unsigned)(t + 1));
    }
    acc2 = acc2n;
  }

  if (owner) out[b * 256 + tid] = hout;
}

extern "C" void kernel_launch(void* const* d_in, const int* in_sizes, int n_in,
                              void* d_out, int out_size, void* d_ws, size_t ws_size,
                              hipStream_t stream) {
  const float* p   = (const float*)d_in[0];
  const float* q   = (const float*)d_in[1];
  const float* v0  = (const float*)d_in[2];
  const float* Wpu = (const float*)d_in[3];
  const float* Wqu = (const float*)d_in[4];
  const float* Wpv = (const float*)d_in[5];
  const float* Wih = (const float*)d_in[6];
  const float* Whh = (const float*)d_in[7];
  const float* bih = (const float*)d_in[8];
  const float* bhh = (const float*)d_in[9];
  float* out = (float*)d_out;

  char* ws = (char*)d_ws;
  unsigned short* Wh  = (unsigned short*)(ws + 0x000000);  // 1,310,720 B
  unsigned short* Wm  = (unsigned short*)(ws + 0x140000);  // 1,310,720 B
  float*    G      = (float*)(ws + 0x280000);              //   393,216 B
  float*    vstate = (float*)(ws + 0x2E0000);              //    65,536 B
  unsigned* flags  = (unsigned*)(ws + 0x2F0000);           //     8,192 B
  float*    qs     = (float*)(ws + 0x300000);              //    65,536 B
  float*    zbv    = (float*)(ws + 0x310000);              //    65,536 B
  float*    WquT   = (float*)(ws + 0x320000);              //   262,144 B
  unsigned short* KbH = (unsigned short*)(ws + 0x360000);  // 8,388,608 B
  unsigned short* KbM = (unsigned short*)(ws + 0xB60000);  // 8,388,608 B
  if (ws_size < 0x1360000u) return;

  const int prep_items = WCOLS * 256 + 65536 + B_N * 256 + 2048;   // 739,328
  prep_kernel<<<(prep_items + 255) / 256, 256, 0, stream>>>(
      Wpu, Wqu, Wpv, Wih, Whh, v0, Wh, Wm, WquT, vstate, flags);

  prep_qz<<<64, 256, 0, stream>>>(q, WquT, qs, zbv);

  const size_t k_smem = 128 * 257 * sizeof(float);          // 131,584 B
  hipFuncSetAttribute(reinterpret_cast<const void*>(prep_K),
                      hipFuncAttributeMaxDynamicSharedMemorySize, (int)k_smem);
  prep_K<<<256, 256, k_smem, stream>>>(q, WquT, KbH, KbM);

  // 128 WGs = 8 groups x 16 members (256 threads each).
  pq_main<<<NGRP * GWGS, NT, 0, stream>>>(p, bih, bhh, Wh, Wm, KbH, KbM, qs, zbv,
                                          G, vstate, flags, out);
}

// Round 7
// 16069.083 us; speedup vs baseline: 1.5786x; 1.0089x over previous
//
#include <hip/hip_runtime.h>

#define T_LEN 1024
#define B_N   64
#define D_N   256
#define Q_N   128
#define WCOLS 2560      // Wcat: 256 pu | 256 pv | 1024 gi | 1024 gh  (w cols deleted)
#define GROW  1536      // exchanged row: 512 (pu|pv) + 1024 (gi+gh summed)
#define NT    256
#define NGRP  8         // groups
#define GB    8         // batches per group (owners = members 0..7)
#define GWGS  16        // WGs per group (64 weight waves)
#define FSTRIDE 32      // one flag per 128B line (32 dwords)

typedef __attribute__((ext_vector_type(8))) short short8;
typedef __attribute__((ext_vector_type(4))) float floatx4;

#define MFMA16(A, B, C) __builtin_amdgcn_mfma_f32_16x16x32_bf16((A), (B), (C), 0, 0, 0)

__device__ __forceinline__ float fsigmoid(float x) { return 1.f / (1.f + __expf(-x)); }
__device__ __forceinline__ float ftanh(float x) {
  float ax = fabsf(x);
  float e = __expf(-2.f * ax);
  float r = (1.f - e) / (1.f + e);
  return (x < 0.f) ? -r : r;
}

// ---- PROVEN exchange primitives (identical to the 18.3ms baseline) ----------
__device__ __forceinline__ floatx4 ld4_sc(const float* a) {
  floatx4 r;
  asm volatile("global_load_dwordx4 %0, %1, off sc0 sc1" : "=v"(r) : "v"(a) : "memory");
  return r;
}
__device__ __forceinline__ float ld1_sc(const float* a) {
  float r;
  asm volatile("global_load_dword %0, %1, off sc0 sc1" : "=v"(r) : "v"(a) : "memory");
  return r;
}
__device__ __forceinline__ void st1_sc(float* a, float v) {
  asm volatile("global_store_dword %0, %1, off sc0 sc1" :: "v"(a), "v"(v) : "memory");
}
__device__ __forceinline__ void st4_sc(float* a, floatx4 v) {
  asm volatile("global_store_dwordx4 %0, %1, off sc0 sc1" :: "v"(a), "v"(v) : "memory");
}
__device__ __forceinline__ void vm_drain() { asm volatile("s_waitcnt vmcnt(0)" ::: "memory"); }
#define TIE(x) asm volatile("" : "+v"(x))

// 3-term truncation split of A: x = h + m + l + eps
struct Split3 { short8 h, m, l; };
__device__ __forceinline__ Split3 split8(const float* x) {
  union U { unsigned u[4]; short8 s; } H, M, L;
#pragma unroll
  for (int i = 0; i < 4; ++i) {
    float x0 = x[2 * i], x1 = x[2 * i + 1];
    unsigned h0 = __float_as_uint(x0) & 0xffff0000u;
    unsigned h1 = __float_as_uint(x1) & 0xffff0000u;
    float r0 = x0 - __uint_as_float(h0);
    float r1 = x1 - __uint_as_float(h1);
    unsigned m0 = __float_as_uint(r0) & 0xffff0000u;
    unsigned m1 = __float_as_uint(r1) & 0xffff0000u;
    float s0 = r0 - __uint_as_float(m0);
    float s1 = r1 - __uint_as_float(m1);
    H.u[i] = (h0 >> 16) | h1;
    M.u[i] = (m0 >> 16) | m1;
    L.u[i] = (__float_as_uint(s0) >> 16) | (__float_as_uint(s1) & 0xffff0000u);
  }
  Split3 r; r.h = H.s; r.m = M.s; r.l = L.s; return r;
}

// 5-product split MFMA: hh, hm, mh, mm, lh
__device__ __forceinline__ floatx4 mfma5(floatx4 acc, const Split3& A, short8 Bh, short8 Bm) {
  acc = MFMA16(A.l, Bh, acc);
  acc = MFMA16(A.m, Bm, acc);
  acc = MFMA16(A.m, Bh, acc);
  acc = MFMA16(A.h, Bm, acc);
  acc = MFMA16(A.h, Bh, acc);
  return acc;
}

// ---------------- prep: W -> 2-way bf16 split; WquT; vstate=v0; flags=0 ------
__global__ void prep_kernel(const float* __restrict__ Wpu, const float* __restrict__ Wqu,
                            const float* __restrict__ Wpv, const float* __restrict__ Wih,
                            const float* __restrict__ Whh, const float* __restrict__ v0,
                            unsigned short* __restrict__ Wh, unsigned short* __restrict__ Wm,
                            float* __restrict__ WquT,
                            float* __restrict__ vstate, unsigned* __restrict__ flags) {
  int idx = blockIdx.x * 256 + threadIdx.x;
  const int total = WCOLS * 256;                // 655360
  if (idx < total) {
    int n = idx >> 8, k = idx & 255;
    float w;
    if      (n < 256)  w = Wpu[k * 256 + n];            // pu_n = sum_k v_k Wpu[k][n]
    else if (n < 512)  w = Wpv[k * 256 + (n - 256)];    // pv
    else if (n < 1536) w = Wih[(n - 512) * 256 + k];    // gi_j = sum_k v[k] Wih[j][k]
    else               w = Whh[(n - 1536) * 256 + k];   // gh_j = sum_k ut[k] Whh[j][k]
    unsigned hb = __float_as_uint(w) & 0xffff0000u;
    float r1 = w - __uint_as_float(hb);
    Wh[idx] = (unsigned short)(hb >> 16);
    Wm[idx] = (unsigned short)((__float_as_uint(r1) & 0xffff0000u) >> 16);
  } else if (idx < total + 65536) {
    int i = idx - total, n = i >> 8, k = i & 255;
    WquT[n * 256 + k] = Wqu[k * 256 + n];               // WquT[n][k] = Wqu[k][n]
  } else if (idx < total + 65536 + B_N * 256) {
    int i = idx - total - 65536;
    vstate[i] = v0[i];
  } else if (idx < total + 65536 + B_N * 256 + 8192) {
    flags[idx - total - 65536 - B_N * 256] = 0u;        // 32KB padded flag area
  }
}

// ---------------- prep_qz: qs_b = sum_j q_j ; z_b = Wqu @ qs_b ---------------
__global__ void prep_qz(const float* __restrict__ q, const float* __restrict__ WquT,
                        float* __restrict__ qsout, float* __restrict__ zbout) {
  __shared__ float qsh[256];
  const int b = blockIdx.x, tid = threadIdx.x;
  float s = 0.f;
  for (int j = 0; j < Q_N; ++j) s += q[((size_t)j * B_N + b) * D_N + tid];
  qsout[b * 256 + tid] = s;
  qsh[tid] = s;
  __syncthreads();
  float z = 0.f;
  for (int n = 0; n < 256; ++n) z += WquT[n * 256 + tid] * qsh[n];
  zbout[b * 256 + tid] = z;                     // z_b[k] = sum_n Wqu[k][n] qs_n
}

// ---------------- prep_K: K_b = Q^T (Q Wqu^T), bf16 2-way split --------------
// K_b[i][k] = sum_n M_b[i][n] Wqu[k][n]; md = K_b v. Block = (batch, i-chunk of 64).
__global__ void prep_K(const float* __restrict__ q, const float* __restrict__ WquT,
                       unsigned short* __restrict__ KbH, unsigned short* __restrict__ KbM) {
  extern __shared__ float qb[];                 // 128 x 257 (pad)
  const int b = blockIdx.x >> 2, ic = blockIdx.x & 3, tid = threadIdx.x;
  for (int j = 0; j < Q_N; ++j)
    qb[j * 257 + tid] = q[((size_t)j * B_N + b) * D_N + tid];
  __syncthreads();
  float Kacc[64];
#pragma unroll
  for (int i = 0; i < 64; ++i) Kacc[i] = 0.f;
  const int i0 = ic * 64;
  for (int qc = 0; qc < 16; ++qc) {             // chunks of 8 q-rows
    float Pq[8];
#pragma unroll
    for (int qq = 0; qq < 8; ++qq) Pq[qq] = 0.f;
    for (int n = 0; n < 256; ++n) {             // P[q][k=tid] = sum_n Q[q][n] WquT[n][k]
      float wv = WquT[n * 256 + tid];
#pragma unroll
      for (int qq = 0; qq < 8; ++qq) Pq[qq] += qb[(qc * 8 + qq) * 257 + n] * wv;
    }
#pragma unroll
    for (int i = 0; i < 64; ++i) {              // K[i][k] += sum_q Q[q][i] P[q][k]
      float a = 0.f;
#pragma unroll
      for (int qq = 0; qq < 8; ++qq) a += qb[(qc * 8 + qq) * 257 + i0 + i] * Pq[qq];
      Kacc[i] += a;
    }
  }
#pragma unroll
  for (int i = 0; i < 64; ++i) {
    float x = Kacc[i];
    unsigned hb = __float_as_uint(x) & 0xffff0000u;
    float r1 = x - __uint_as_float(hb);
    size_t o = ((size_t)b * 256 + i0 + i) * 256 + tid;
    KbH[o] = (unsigned short)(hb >> 16);
    KbM[o] = (unsigned short)((__float_as_uint(r1) & 0xffff0000u) >> 16);
  }
}

// ---------------- group sync: NF flags, ONE per 128B line, NF pollers --------
// Anti-hot-line discipline: each member signals its own padded line; only NF
// lanes poll (one lane per line). Same proven agent-scope atomic semantics.
template<int NF>
__device__ __forceinline__ void wait_flags(const unsigned* f, unsigned val) {
  if (threadIdx.x < 64) {
    const int lane = threadIdx.x;
    const unsigned* fp = f + lane * FSTRIDE;
    unsigned v = val;
    if (lane < NF)
      v = __hip_atomic_load(fp, __ATOMIC_RELAXED, __HIP_MEMORY_SCOPE_AGENT);
    while (__any((int)(v < val))) {
      __builtin_amdgcn_s_sleep(1);
      if (lane < NF)
        v = __hip_atomic_load(fp, __ATOMIC_RELAXED, __HIP_MEMORY_SCOPE_AGENT);
    }
  }
  __syncthreads();
}
__device__ __forceinline__ void signal_flag(unsigned* f, unsigned val) {
  vm_drain();                        // my wave's sc1 stores reached coherence pt
  __syncthreads();                   // all waves drained
  if (threadIdx.x == 0)
    __hip_atomic_store(f, val, __ATOMIC_RELAXED, __HIP_MEMORY_SCOPE_AGENT);
}

// ---------------- main: 128 WGs x 256 thr; 8 groups x 16 members -------------
// Owners (m<8): gi+gh tiles + md = K_b v via MFMA (off critical path) + phase 2.
// Non-owners (m>=8): pu|pv tile + gi+gh tiles.
//   md = (M Wqu^T) v = K_b v ;  r = v.z_b + 128*beta.
__launch_bounds__(NT, 1)
__global__ void pq_main(const float* __restrict__ p,
                        const float* __restrict__ bih, const float* __restrict__ bhh,
                        const unsigned short* __restrict__ Wh,
                        const unsigned short* __restrict__ Wm,
                        const unsigned short* __restrict__ KbH,
                        const unsigned short* __restrict__ KbM,
                        const float* __restrict__ qs, const float* __restrict__ zb,
                        float* G, float* vstate, unsigned* flags,
                        float* __restrict__ out) {
  __shared__ float2 red2[256];
  __shared__ float scal[2];          // beta, 1/r
  __shared__ float mdl[256];         // owner: md output routed via LDS
  __shared__ float LDSg[8][128];     // scatter staging

  const int tid   = threadIdx.x;
  const int bid   = blockIdx.x;
  const int g     = bid & 7;             // group
  const int m     = bid >> 3;            // member 0..15
  const bool owner = (m < GB);
  const int b     = g * GB + (m & 7);
  const int lane  = tid & 63;
  const int widx  = tid >> 6;            // wave 0..3
  const int gwave = m * 4 + widx;        // 0..63: gate tile index (all members)
  const int n2    = 512  + gwave * 16;   // gi cols
  const int n3    = 1536 + gwave * 16;   // gh cols
  const int row   = lane & 15;
  const int arow  = lane & 7;            // A-row: batches 0..7 (rows 8..15 dup)
  const int kb    = lane >> 4;

  // padded flag lines: group g owns 1024 dwords (4KB)
  unsigned* flagsA = flags + g * 1024;          // 16 lines
  unsigned* flagsB = flags + g * 1024 + 512;    // 8 lines

  const float bI = bih[tid]       + bhh[tid];
  const float bF = bih[256 + tid] + bhh[256 + tid];
  const float bG = bih[512 + tid] + bhh[512 + tid];
  const float bO = bih[768 + tid] + bhh[768 + tid];
  const float qsd = qs[b * 256 + tid];
  const float zbd = zb[b * 256 + tid];
  float vprev = vstate[(size_t)b * 256 + tid];

  // ---- register-resident B fragments ----
  short8 Bhg[8], Bmg[8], Bh2[8], Bm2[8], Bh1[8], Bm1[8];
#pragma unroll
  for (int ks = 0; ks < 8; ++ks) {
    int ko = ks * 32 + kb * 8;
    int c2 = (n2 + row) * 256 + ko;
    int c3 = (n3 + row) * 256 + ko;
    Bhg[ks] = *(const short8*)&Wh[c2];  Bmg[ks] = *(const short8*)&Wm[c2];
    Bh2[ks] = *(const short8*)&Wh[c3];  Bm2[ks] = *(const short8*)&Wm[c3];
  }
  if (!owner) {
    const int n1 = ((m - 8) * 4 + widx) * 16;   // pu|pv cols, 16 per wave
#pragma unroll
    for (int ks = 0; ks < 8; ++ks) {
      int ko = ks * 32 + kb * 8;
      int c1 = (n1 + row) * 256 + ko;
      Bh1[ks] = *(const short8*)&Wh[c1];  Bm1[ks] = *(const short8*)&Wm[c1];
    }
  }

  // ---- gh tile for t=0 from p[0] ----
  floatx4 acc2 = {0.f, 0.f, 0.f, 0.f};
  {
    const float* pb = p + ((size_t)0 * B_N + g * GB) * D_N;
#pragma unroll
    for (int ks = 0; ks < 8; ++ks) {
      float xa[8];
      const float* pr = pb + arow * D_N + ks * 32 + kb * 8;
      *(float4*)&xa[0] = *(const float4*)pr;
      *(float4*)&xa[4] = *(const float4*)(pr + 4);
      Split3 A = split8(xa);
      acc2 = mfma5(acc2, A, Bh2[ks], Bm2[ks]);
    }
  }

  float hout = 0.f;
  const float* vb = vstate + (size_t)(g * GB) * 256;

  for (int t = 0; t < T_LEN; ++t) {
    // ---- wait all v_t stored; issue v-frag loads, ONE drain ----
    wait_flags<GB>(flagsB, (unsigned)t);

    floatx4 va[8][2];
#pragma unroll
    for (int ks = 0; ks < 8; ++ks) {
      const float* vr = vb + arow * 256 + ks * 32 + kb * 8;
      va[ks][0] = ld4_sc(vr);
      va[ks][1] = ld4_sc(vr + 4);
    }
    vm_drain();
#pragma unroll
    for (int ks = 0; ks < 8; ++ks) { TIE(va[ks][0]); TIE(va[ks][1]); }

    floatx4 acc1 = {0.f, 0.f, 0.f, 0.f}, accg = {0.f, 0.f, 0.f, 0.f};
#pragma unroll
    for (int ks = 0; ks < 8; ++ks) {
      float xa[8];
      *(floatx4*)&xa[0] = va[ks][0];
      *(floatx4*)&xa[4] = va[ks][1];
      Split3 A = split8(xa);
      accg = mfma5(accg, A, Bhg[ks], Bmg[ks]);
      if (!owner) acc1 = mfma5(acc1, A, Bh1[ks], Bm1[ks]);
    }

    // ---- stage G slice to LDS, store coalesced dwordx4 (sc0 sc1) ----
    {
      int col = lane & 15, r0q = lane >> 4;
      if (r0q < 2) {                       // rows 0..7 (8..15 are dups)
#pragma unroll
        for (int r = 0; r < 4; ++r) {
          int rr = r0q * 4 + r;
          if (owner) {
            LDSg[rr][widx * 16 + col] = accg[r] + acc2[r];            // gates
          } else {
            LDSg[rr][widx * 16 + col] = acc1[r];                      // pu|pv
            LDSg[rr][64 + widx * 16 + col] = accg[r] + acc2[r];       // gates
          }
        }
      }
    }
    __syncthreads();
    if (owner) {
      if (tid < 128) {
        int r = tid >> 4, c = (tid & 15) * 4;
        st4_sc(&G[(size_t)(g * GB + r) * GROW + 512 + m * 64 + c],
               *(const floatx4*)&LDSg[r][c]);
      }
    } else {
      if (tid < 128) {
        int r = tid >> 4, c = (tid & 15) * 4;
        st4_sc(&G[(size_t)(g * GB + r) * GROW + (m - 8) * 64 + c],
               *(const floatx4*)&LDSg[r][c]);
      } else {
        int t2 = tid - 128, r = t2 >> 4, c = (t2 & 15) * 4;
        st4_sc(&G[(size_t)(g * GB + r) * GROW + 512 + m * 64 + c],
               *(const floatx4*)&LDSg[r][64 + c]);
      }
    }
    signal_flag(flagsA + m * FSTRIDE, (unsigned)(t + 1));

    // ---- owner: md = K_b v via MFMA (off critical path; reuses va) ----
    if (owner) {
      floatx4 md0 = {0.f,0.f,0.f,0.f}, md1 = {0.f,0.f,0.f,0.f};
      floatx4 md2 = {0.f,0.f,0.f,0.f}, md3 = {0.f,0.f,0.f,0.f};
      const unsigned short* KH = KbH + ((size_t)b * 256 + widx * 64) * 256;
      const unsigned short* KM = KbM + ((size_t)b * 256 + widx * 64) * 256;
#pragma unroll
      for (int ks = 0; ks < 8; ++ks) {
        float xa[8];
        *(floatx4*)&xa[0] = va[ks][0];
        *(floatx4*)&xa[4] = va[ks][1];
        Split3 A = split8(xa);
        int ko = ks * 32 + kb * 8;
        md0 = mfma5(md0, A, *(const short8*)&KH[(      row) * 256 + ko],
                            *(const short8*)&KM[(      row) * 256 + ko]);
        md1 = mfma5(md1, A, *(const short8*)&KH[(16  + row) * 256 + ko],
                            *(const short8*)&KM[(16  + row) * 256 + ko]);
        md2 = mfma5(md2, A, *(const short8*)&KH[(32  + row) * 256 + ko],
                            *(const short8*)&KM[(32  + row) * 256 + ko]);
        md3 = mfma5(md3, A, *(const short8*)&KH[(48  + row) * 256 + ko],
                            *(const short8*)&KM[(48  + row) * 256 + ko]);
      }
      // C layout: row=(lane>>4)*4+r, col=lane&15. Row m carries v_b.
      if ((lane >> 4) == (m >> 2)) {
        int r = m & 3, c = lane & 15;
        mdl[widx * 64 +  0 + c] = md0[r];
        mdl[widx * 64 + 16 + c] = md1[r];
        mdl[widx * 64 + 32 + c] = md2[r];
        mdl[widx * 64 + 48 + c] = md3[r];
      }
    }

    // ---- next-step gh tile: off the critical path ----
    floatx4 acc2n = {0.f, 0.f, 0.f, 0.f};
    if (t + 1 < T_LEN) {
      const float* pb = p + ((size_t)(t + 1) * B_N + g * GB) * D_N;
#pragma unroll
      for (int ks = 0; ks < 8; ++ks) {
        float xa[8];
        const float* pr = pb + arow * D_N + ks * 32 + kb * 8;
        *(float4*)&xa[0] = *(const float4*)pr;
        *(float4*)&xa[4] = *(const float4*)(pr + 4);
        Split3 A = split8(xa);
        acc2n = mfma5(acc2n, A, Bh2[ks], Bm2[ks]);
      }
    }

    // ---- phase 2 (owners only) ----
    if (owner) {
      wait_flags<GWGS>(flagsA, (unsigned)(t + 1));
      const float* gr = G + (size_t)b * GROW;
      float utd = p[((size_t)t * B_N + b) * D_N + tid];
      float pu = ld1_sc(gr + tid);
      float pv = ld1_sc(gr + 256 + tid);
      float g0 = ld1_sc(gr + 512 + tid);
      float g1 = ld1_sc(gr + 768 + tid);
      float g2 = ld1_sc(gr + 1024 + tid);
      float g3 = ld1_sc(gr + 1280 + tid);
      vm_drain();
      TIE(pu); TIE(pv); TIE(g0); TIE(g1); TIE(g2); TIE(g3);

      red2[tid] = make_float2(pu * utd + pv * vprev, vprev * zbd);
      __syncthreads();
      if (tid < 64) {
        float2 s = red2[tid];
        float2 s1 = red2[tid + 64], s2 = red2[tid + 128], s3 = red2[tid + 192];
        s.x += s1.x + s2.x + s3.x;  s.y += s1.y + s2.y + s3.y;
#pragma unroll
        for (int off = 1; off < 64; off <<= 1) {
          s.x += __shfl_xor(s.x, off);
          s.y += __shfl_xor(s.y, off);
        }
        if (tid == 0) {
          float beta = s.x;
          float r = s.y + 128.f * beta;      // r = v.z_b + Q*beta
          scal[0] = beta;
          scal[1] = 1.f / r;
        }
      }
      __syncthreads();

      float beta = scal[0], invr = scal[1];
      float cctx = (mdl[tid] + beta * qsd) * invr;
      float cn = fsigmoid(g1 + bF) * cctx + fsigmoid(g0 + bI) * ftanh(g2 + bG);
      hout = fsigmoid(g3 + bO) * ftanh(cn);
      st1_sc(&vstate[(size_t)b * 256 + tid], hout);
      vprev = hout;
      signal_flag(flagsB + m * FSTRIDE, (unsigned)(t + 1));
    }
    acc2 = acc2n;
  }

  if (owner) out[b * 256 + tid] = hout;
}

extern "C" void kernel_launch(void* const* d_in, const int* in_sizes, int n_in,
                              void* d_out, int out_size, void* d_ws, size_t ws_size,
                              hipStream_t stream) {
  const float* p   = (const float*)d_in[0];
  const float* q   = (const float*)d_in[1];
  const float* v0  = (const float*)d_in[2];
  const float* Wpu = (const float*)d_in[3];
  const float* Wqu = (const float*)d_in[4];
  const float* Wpv = (const float*)d_in[5];
  const float* Wih = (const float*)d_in[6];
  const float* Whh = (const float*)d_in[7];
  const float* bih = (const float*)d_in[8];
  const float* bhh = (const float*)d_in[9];
  float* out = (float*)d_out;

  char* ws = (char*)d_ws;
  unsigned short* Wh  = (unsigned short*)(ws + 0x000000);  // 1,310,720 B
  unsigned short* Wm  = (unsigned short*)(ws + 0x140000);  // 1,310,720 B
  float*    G      = (float*)(ws + 0x280000);              //   393,216 B
  float*    vstate = (float*)(ws + 0x2E0000);              //    65,536 B
  unsigned* flags  = (unsigned*)(ws + 0x2F0000);           //    32,768 B (padded lines)
  float*    qs     = (float*)(ws + 0x300000);              //    65,536 B
  float*    zbv    = (float*)(ws + 0x310000);              //    65,536 B
  float*    WquT   = (float*)(ws + 0x320000);              //   262,144 B
  unsigned short* KbH = (unsigned short*)(ws + 0x360000);  // 8,388,608 B
  unsigned short* KbM = (unsigned short*)(ws + 0xB60000);  // 8,388,608 B
  if (ws_size < 0x1360000u) return;

  const int prep_items = WCOLS * 256 + 65536 + B_N * 256 + 8192;   // 745,472
  prep_kernel<<<(prep_items + 255) / 256, 256, 0, stream>>>(
      Wpu, Wqu, Wpv, Wih, Whh, v0, Wh, Wm, WquT, vstate, flags);

  prep_qz<<<64, 256, 0, stream>>>(q, WquT, qs, zbv);

  const size_t k_smem = 128 * 257 * sizeof(float);          // 131,584 B
  hipFuncSetAttribute(reinterpret_cast<const void*>(prep_K),
                      hipFuncAttributeMaxDynamicSharedMemorySize, (int)k_smem);
  prep_K<<<256, 256, k_smem, stream>>>(q, WquT, KbH, KbM);

  // 128 WGs = 8 groups x 16 members (256 threads each).
  pq_main<<<NGRP * GWGS, NT, 0, stream>>>(p, bih, bhh, Wh, Wm, KbH, KbM, qs, zbv,
                                          G, vstate, flags, out);
}

// Round 8
// 9550.201 us; speedup vs baseline: 2.6562x; 1.6826x over previous
//
#include <hip/hip_runtime.h>

#define T_LEN 1024
#define B_N   64
#define D_N   256
#define Q_N   128
#define WCOLS 2560      // weights: 256 pu | 256 pv | 1024 gi | 1024 gh
#define GROW  1312      // G row: 1024 gates | 256 md | 32 beta-partials
#define NT    256
#define NGRP  8
#define GB    8
#define GWGS  16
#define FSTRIDE 16      // one flag per 64B line
#define VP    260       // vsh row pitch (floats): 260%32==4 -> 8 rows on distinct banks

typedef __attribute__((ext_vector_type(8))) short short8;
typedef __attribute__((ext_vector_type(4))) float floatx4;

#define MFMA16(A, B, C) __builtin_amdgcn_mfma_f32_16x16x32_bf16((A), (B), (C), 0, 0, 0)

__device__ __forceinline__ float fsigmoid(float x) { return 1.f / (1.f + __expf(-x)); }
__device__ __forceinline__ float ftanh(float x) {
  float ax = fabsf(x);
  float e = __expf(-2.f * ax);
  float r = (1.f - e) / (1.f + e);
  return (x < 0.f) ? -r : r;
}

// ---- PROVEN exchange primitives (baseline mechanism) ------------------------
__device__ __forceinline__ floatx4 ld4_sc(const float* a) {
  floatx4 r;
  asm volatile("global_load_dwordx4 %0, %1, off sc0 sc1" : "=v"(r) : "v"(a) : "memory");
  return r;
}
__device__ __forceinline__ float ld1_sc(const float* a) {
  float r;
  asm volatile("global_load_dword %0, %1, off sc0 sc1" : "=v"(r) : "v"(a) : "memory");
  return r;
}
__device__ __forceinline__ void st1_sc(float* a, float v) {
  asm volatile("global_store_dword %0, %1, off sc0 sc1" :: "v"(a), "v"(v) : "memory");
}
__device__ __forceinline__ void st4_sc(float* a, floatx4 v) {
  asm volatile("global_store_dwordx4 %0, %1, off sc0 sc1" :: "v"(a), "v"(v) : "memory");
}
__device__ __forceinline__ void vm_drain() { asm volatile("s_waitcnt vmcnt(0)" ::: "memory"); }
#define TIE(x) asm volatile("" : "+v"(x))

// 3-term truncation split of A: x = h + m + l + eps
struct Split3 { short8 h, m, l; };
__device__ __forceinline__ Split3 split8(const float* x) {
  union U { unsigned u[4]; short8 s; } H, M, L;
#pragma unroll
  for (int i = 0; i < 4; ++i) {
    float x0 = x[2 * i], x1 = x[2 * i + 1];
    unsigned h0 = __float_as_uint(x0) & 0xffff0000u;
    unsigned h1 = __float_as_uint(x1) & 0xffff0000u;
    float r0 = x0 - __uint_as_float(h0);
    float r1 = x1 - __uint_as_float(h1);
    unsigned m0 = __float_as_uint(r0) & 0xffff0000u;
    unsigned m1 = __float_as_uint(r1) & 0xffff0000u;
    float s0 = r0 - __uint_as_float(m0);
    float s1 = r1 - __uint_as_float(m1);
    H.u[i] = (h0 >> 16) | h1;
    M.u[i] = (m0 >> 16) | m1;
    L.u[i] = (__float_as_uint(s0) >> 16) | (__float_as_uint(s1) & 0xffff0000u);
  }
  Split3 r; r.h = H.s; r.m = M.s; r.l = L.s; return r;
}

// 5-product split MFMA
__device__ __forceinline__ floatx4 mfma5(floatx4 acc, const Split3& A, short8 Bh, short8 Bm) {
  acc = MFMA16(A.l, Bh, acc);
  acc = MFMA16(A.m, Bm, acc);
  acc = MFMA16(A.m, Bh, acc);
  acc = MFMA16(A.h, Bm, acc);
  acc = MFMA16(A.h, Bh, acc);
  return acc;
}

// ---------------- prep: W -> bf16 2-way split; WquT; flags=0 -----------------
__global__ void prep_kernel(const float* __restrict__ Wpu, const float* __restrict__ Wqu,
                            const float* __restrict__ Wpv, const float* __restrict__ Wih,
                            const float* __restrict__ Whh,
                            unsigned short* __restrict__ Wh, unsigned short* __restrict__ Wm,
                            float* __restrict__ WquT, unsigned* __restrict__ flags) {
  int idx = blockIdx.x * 256 + threadIdx.x;
  const int total = WCOLS * 256;                // 655360
  if (idx < total) {
    int n = idx >> 8, k = idx & 255;
    float w;
    if      (n < 256)  w = Wpu[k * 256 + n];            // pu
    else if (n < 512)  w = Wpv[k * 256 + (n - 256)];    // pv
    else if (n < 1536) w = Wih[(n - 512) * 256 + k];    // gi
    else               w = Whh[(n - 1536) * 256 + k];   // gh
    unsigned hb = __float_as_uint(w) & 0xffff0000u;
    float r1 = w - __uint_as_float(hb);
    Wh[idx] = (unsigned short)(hb >> 16);
    Wm[idx] = (unsigned short)((__float_as_uint(r1) & 0xffff0000u) >> 16);
  } else if (idx < total + 65536) {
    int i = idx - total, n = i >> 8, k = i & 255;
    WquT[n * 256 + k] = Wqu[k * 256 + n];
  } else if (idx < total + 65536 + 2048) {
    flags[idx - total - 65536] = 0u;
  }
}

// ---------------- prep_qz: qs_b = sum_j q_j ; z_b = Wqu @ qs_b ---------------
__global__ void prep_qz(const float* __restrict__ q, const float* __restrict__ WquT,
                        float* __restrict__ qsout, float* __restrict__ zbout) {
  __shared__ float qsh[256];
  const int b = blockIdx.x, tid = threadIdx.x;
  float s = 0.f;
  for (int j = 0; j < Q_N; ++j) s += q[((size_t)j * B_N + b) * D_N + tid];
  qsout[b * 256 + tid] = s;
  qsh[tid] = s;
  __syncthreads();
  float z = 0.f;
  for (int n = 0; n < 256; ++n) z += WquT[n * 256 + tid] * qsh[n];
  zbout[b * 256 + tid] = z;
}

// ---------------- prep_K: K_b = Q^T (Q Wqu^T), bf16 2-way split --------------
__global__ void prep_K(const float* __restrict__ q, const float* __restrict__ WquT,
                       unsigned short* __restrict__ KbH, unsigned short* __restrict__ KbM) {
  extern __shared__ float qb[];                 // 128 x 257
  const int b = blockIdx.x >> 2, ic = blockIdx.x & 3, tid = threadIdx.x;
  for (int j = 0; j < Q_N; ++j)
    qb[j * 257 + tid] = q[((size_t)j * B_N + b) * D_N + tid];
  __syncthreads();
  float Kacc[64];
#pragma unroll
  for (int i = 0; i < 64; ++i) Kacc[i] = 0.f;
  const int i0 = ic * 64;
  for (int qc = 0; qc < 16; ++qc) {
    float Pq[8];
#pragma unroll
    for (int qq = 0; qq < 8; ++qq) Pq[qq] = 0.f;
    for (int n = 0; n < 256; ++n) {
      float wv = WquT[n * 256 + tid];
#pragma unroll
      for (int qq = 0; qq < 8; ++qq) Pq[qq] += qb[(qc * 8 + qq) * 257 + n] * wv;
    }
#pragma unroll
    for (int i = 0; i < 64; ++i) {
      float a = 0.f;
#pragma unroll
      for (int qq = 0; qq < 8; ++qq) a += qb[(qc * 8 + qq) * 257 + i0 + i] * Pq[qq];
      Kacc[i] += a;
    }
  }
#pragma unroll
  for (int i = 0; i < 64; ++i) {
    float x = Kacc[i];
    unsigned hb = __float_as_uint(x) & 0xffff0000u;
    float r1 = x - __uint_as_float(hb);
    size_t o = ((size_t)b * 256 + i0 + i) * 256 + tid;
    KbH[o] = (unsigned short)(hb >> 16);
    KbM[o] = (unsigned short)((__float_as_uint(r1) & 0xffff0000u) >> 16);
  }
}

// ---------------- group sync ------------------------------------------------
template<int NF>
__device__ __forceinline__ void wait_flags(const unsigned* f, unsigned val) {
  if (threadIdx.x < 64) {
    const int lane = threadIdx.x;
    const unsigned* fp = f + lane * FSTRIDE;
    unsigned v = val;
    if (lane < NF)
      v = __hip_atomic_load(fp, __ATOMIC_RELAXED, __HIP_MEMORY_SCOPE_AGENT);
    while (__any((int)(v < val))) {
      __builtin_amdgcn_s_sleep(1);
      if (lane < NF)
        v = __hip_atomic_load(fp, __ATOMIC_RELAXED, __HIP_MEMORY_SCOPE_AGENT);
    }
  }
  __syncthreads();
}
__device__ __forceinline__ void signal_flag(unsigned* f, unsigned val) {
  vm_drain();
  __syncthreads();
  if (threadIdx.x == 0)
    __hip_atomic_store(f, val, __ATOMIC_RELAXED, __HIP_MEMORY_SCOPE_AGENT);
}

// ---------------- main: ONE barrier hop per step -----------------------------
// 128 WGs = 8 groups x 16 members. Phase 1: gi + md (K_b MFMA, r6-verified) +
// pu/pv partial-beta producer-side; exchange G = gates|md|partials, signal.
// Phase 2: ALL WGs gather their 8-batch slice and compute v_{t+1} REDUNDANTLY
// + locally (LDS) -> no v broadcast, no second hop. G double-buffered:
// waitA(t+1) transitively proves all WGs passed gather(t-1) -> overwrite safe.
__launch_bounds__(NT, 1)
__global__ void pq_main(const float* __restrict__ p,
                        const float* __restrict__ bih, const float* __restrict__ bhh,
                        const unsigned short* __restrict__ Wh,
                        const unsigned short* __restrict__ Wm,
                        const unsigned short* __restrict__ KbH,
                        const unsigned short* __restrict__ KbM,
                        const float* __restrict__ qs, const float* __restrict__ zb,
                        const float* __restrict__ v0,
                        float* G0, float* G1, unsigned* flags,
                        float* __restrict__ out) {
  __shared__ __align__(16) float vsh[8 * VP];   // v_t block, bank-spread pitch
  __shared__ __align__(16) float LDSg[8][64];   // gate staging
  __shared__ float2 bsh[8];
  __shared__ float bL[1024];                    // combined biases
  __shared__ float qsL[2048];
  __shared__ float zL[2048];

  const int tid  = threadIdx.x;
  const int bid  = blockIdx.x;
  const int g    = bid & 7;
  const int m    = bid >> 3;
  const int lane = tid & 63;
  const int widx = tid >> 6;
  const int gw   = m * 4 + widx;          // 0..63 group-wave
  const int n2   = 512  + gw * 16;        // gi cols
  const int n3   = 1536 + gw * 16;        // gh cols
  const int gwp  = (m - 8) * 4 + widx;    // pu/pv wave id (m>=8): 0..31
  const int n1   = gwp * 16;              // pu/pv col base
  const int bmd  = gw >> 3;               // md batch-in-group 0..7
  const int ct0  = (gw & 7) * 2;          // md col-tiles ct0, ct0+1
  const int bmdg = g * GB + bmd;
  const int row  = lane & 15;
  const int arow = lane & 7;
  const int kb   = lane >> 4;
  const int r0q  = lane >> 4;

  unsigned* flagsA = flags + g * (GWGS * FSTRIDE);

  const int bi = tid >> 5, j = tid & 31, nb = j * 8;
  const int bb = g * GB + bi;

  // constants -> LDS (saves ~48 VGPR)
  for (int i = tid; i < 1024; i += NT) bL[i] = bih[i] + bhh[i];
  for (int i = tid; i < 2048; i += NT) {
    int r = i >> 8, c = i & 255;
    qsL[i] = qs[(size_t)(g * GB + r) * 256 + c];
    zL[i]  = zb[(size_t)(g * GB + r) * 256 + c];
    vsh[r * VP + c] = v0[(size_t)(g * GB + r) * 256 + c];
  }
  __syncthreads();

  // register-resident B fragments: gi, gh, 2x md(K_b), pu/pv (m>=8)
  short8 Bhg[8], Bmg[8], Bh2[8], Bm2[8], Bh1[8], Bm1[8];
  short8 Kh0[8], Km0[8], Kh1[8], Km1[8];
#pragma unroll
  for (int ks = 0; ks < 8; ++ks) {
    int ko = ks * 32 + kb * 8;
    int c2 = (n2 + row) * 256 + ko;
    int c3 = (n3 + row) * 256 + ko;
    Bhg[ks] = *(const short8*)&Wh[c2];  Bmg[ks] = *(const short8*)&Wm[c2];
    Bh2[ks] = *(const short8*)&Wh[c3];  Bm2[ks] = *(const short8*)&Wm[c3];
    size_t k0 = ((size_t)bmdg * 256 + ct0 * 16 + row) * 256 + ko;
    size_t k1 = k0 + (size_t)16 * 256;
    Kh0[ks] = *(const short8*)&KbH[k0]; Km0[ks] = *(const short8*)&KbM[k0];
    Kh1[ks] = *(const short8*)&KbH[k1]; Km1[ks] = *(const short8*)&KbM[k1];
    if (m >= 8) {
      int c1 = (n1 + row) * 256 + ko;
      Bh1[ks] = *(const short8*)&Wh[c1];  Bm1[ks] = *(const short8*)&Wm[c1];
    }
  }

  // gh tile for t=0
  floatx4 acc2 = {0.f, 0.f, 0.f, 0.f};
  {
    const float* pb = p + ((size_t)0 * B_N + g * GB) * D_N;
#pragma unroll
    for (int ks = 0; ks < 8; ++ks) {
      float xa[8];
      const float* pr = pb + arow * D_N + ks * 32 + kb * 8;
      *(float4*)&xa[0] = *(const float4*)pr;
      *(float4*)&xa[4] = *(const float4*)(pr + 4);
      Split3 A = split8(xa);
      acc2 = mfma5(acc2, A, Bh2[ks], Bm2[ks]);
    }
  }

  for (int t = 0; t < T_LEN; ++t) {
    float* Gc = (t & 1) ? G1 : G0;

    // ---- phase 1: all tiles from local vsh ----
    floatx4 accg = {0.f,0.f,0.f,0.f}, acc1 = {0.f,0.f,0.f,0.f};
    floatx4 mdA = {0.f,0.f,0.f,0.f}, mdB = {0.f,0.f,0.f,0.f};
#pragma unroll
    for (int ks = 0; ks < 8; ++ks) {
      float xa[8];
      *(floatx4*)&xa[0] = *(const floatx4*)&vsh[arow * VP + ks * 32 + kb * 8];
      *(floatx4*)&xa[4] = *(const floatx4*)&vsh[arow * VP + ks * 32 + kb * 8 + 4];
      Split3 A = split8(xa);
      accg = mfma5(accg, A, Bhg[ks], Bmg[ks]);
      mdA  = mfma5(mdA,  A, Kh0[ks], Km0[ks]);
      mdB  = mfma5(mdB,  A, Kh1[ks], Km1[ks]);
      if (m >= 8) acc1 = mfma5(acc1, A, Bh1[ks], Bm1[ks]);
    }

    // gates -> staging (rows 0..7; 8..15 are dups)
    if (r0q < 2) {
#pragma unroll
      for (int r = 0; r < 4; ++r)
        LDSg[r0q * 4 + r][widx * 16 + row] = accg[r] + acc2[r];
    }
    // md: extract row bmd, direct 64B-contiguous stores
    if (r0q == (bmd >> 2)) {
      int rg = bmd & 3;
      st1_sc(&Gc[(size_t)bmdg * GROW + 1024 + ct0 * 16 + row], mdA[rg]);
      st1_sc(&Gc[(size_t)bmdg * GROW + 1024 + (ct0 + 1) * 16 + row], mdB[rg]);
    }
    // pu/pv: producer-side partial beta (dot with ut / v), one scalar per row
    if (m >= 8) {
      float pr4[4];
#pragma unroll
      for (int r = 0; r < 4; ++r) {
        pr4[r] = 0.f;
        if (r0q < 2) {
          int rr = r0q * 4 + r;
          float w;
          if (n1 < 256)
            w = p[((size_t)t * B_N + g * GB + rr) * D_N + n1 + row];      // ut
          else
            w = vsh[rr * VP + (n1 - 256) + row];                          // v_t
          pr4[r] = acc1[r] * w;
        }
      }
#pragma unroll
      for (int off = 1; off < 16; off <<= 1) {
#pragma unroll
        for (int r = 0; r < 4; ++r) pr4[r] += __shfl_xor(pr4[r], off);
      }
      if (row == 0 && r0q < 2) {
#pragma unroll
        for (int r = 0; r < 4; ++r)
          st1_sc(&Gc[(size_t)(g * GB + r0q * 4 + r) * GROW + 1280 + gwp], pr4[r]);
      }
    }
    __syncthreads();
    if (tid < 128) {                      // coalesced gate store
      int r = tid >> 4, c = (tid & 15) * 4;
      st4_sc(&Gc[(size_t)(g * GB + r) * GROW + m * 64 + c],
             *(const floatx4*)&LDSg[r][c]);
    }
    signal_flag(flagsA + m * FSTRIDE, (unsigned)(t + 1));

    // ---- gh prefetch for t+1 (hides in the wait window) ----
    floatx4 acc2n = {0.f,0.f,0.f,0.f};
    if (t + 1 < T_LEN) {
      const float* pb = p + ((size_t)(t + 1) * B_N + g * GB) * D_N;
#pragma unroll
      for (int ks = 0; ks < 8; ++ks) {
        float xa[8];
        const float* pr = pb + arow * D_N + ks * 32 + kb * 8;
        *(float4*)&xa[0] = *(const float4*)pr;
        *(float4*)&xa[4] = *(const float4*)(pr + 4);
        Split3 A = split8(xa);
        acc2n = mfma5(acc2n, A, Bh2[ks], Bm2[ks]);
      }
    }

    // ---- the single hop ----
    wait_flags<GWGS>(flagsA, (unsigned)(t + 1));

    // ---- redundant local phase 2: gather slice, reduce, LSTM -> vsh ----
    const float* gr = Gc + (size_t)bb * GROW;
    floatx4 A0 = ld4_sc(gr + nb),        A1 = ld4_sc(gr + nb + 4);
    floatx4 B0 = ld4_sc(gr + 256 + nb),  B1 = ld4_sc(gr + 256 + nb + 4);
    floatx4 C0 = ld4_sc(gr + 512 + nb),  C1 = ld4_sc(gr + 512 + nb + 4);
    floatx4 D0 = ld4_sc(gr + 768 + nb),  D1 = ld4_sc(gr + 768 + nb + 4);
    floatx4 M0 = ld4_sc(gr + 1024 + nb), M1 = ld4_sc(gr + 1024 + nb + 4);
    float part = ld1_sc(gr + 1280 + j);
    vm_drain();
    TIE(A0); TIE(A1); TIE(B0); TIE(B1); TIE(C0); TIE(C1);
    TIE(D0); TIE(D1); TIE(M0); TIE(M1); TIE(part);
    float g0v[8], g1v[8], g2v[8], g3v[8], md8[8];
    *(floatx4*)&g0v[0] = A0; *(floatx4*)&g0v[4] = A1;
    *(floatx4*)&g1v[0] = B0; *(floatx4*)&g1v[4] = B1;
    *(floatx4*)&g2v[0] = C0; *(floatx4*)&g2v[4] = C1;
    *(floatx4*)&g3v[0] = D0; *(floatx4*)&g3v[4] = D1;
    *(floatx4*)&md8[0] = M0; *(floatx4*)&md8[4] = M1;

    float v8[8];
    *(floatx4*)&v8[0] = *(const floatx4*)&vsh[bi * VP + nb];
    *(floatx4*)&v8[4] = *(const floatx4*)&vsh[bi * VP + nb + 4];
    float rz = 0.f;
#pragma unroll
    for (int e = 0; e < 8; ++e) rz += zL[bi * 256 + nb + e] * v8[e];
    float sx = part, sy = rz;
#pragma unroll
    for (int off = 1; off < 32; off <<= 1) {
      sx += __shfl_xor(sx, off);
      sy += __shfl_xor(sy, off);
    }
    if (j == 0) bsh[bi] = make_float2(sx, sy);
    __syncthreads();
    float beta = bsh[bi].x;
    float invr = 1.f / (bsh[bi].y + 128.f * beta);   // r = v.z + Q*beta

    float h8[8];
#pragma unroll
    for (int e = 0; e < 8; ++e) {
      int n = nb + e;
      float cctx = (md8[e] + beta * qsL[bi * 256 + n]) * invr;
      float cn = fsigmoid(g1v[e] + bL[256 + n]) * cctx
               + fsigmoid(g0v[e] + bL[n]) * ftanh(g2v[e] + bL[512 + n]);
      h8[e] = fsigmoid(g3v[e] + bL[768 + n]) * ftanh(cn);
    }
    *(floatx4*)&vsh[bi * VP + nb]     = *(const floatx4*)&h8[0];
    *(floatx4*)&vsh[bi * VP + nb + 4] = *(const floatx4*)&h8[4];
    __syncthreads();
    acc2 = acc2n;
  }

  if (m < GB) out[(size_t)(g * GB + m) * 256 + tid] = vsh[m * VP + tid];
}

extern "C" void kernel_launch(void* const* d_in, const int* in_sizes, int n_in,
                              void* d_out, int out_size, void* d_ws, size_t ws_size,
                              hipStream_t stream) {
  const float* p   = (const float*)d_in[0];
  const float* q   = (const float*)d_in[1];
  const float* v0  = (const float*)d_in[2];
  const float* Wpu = (const float*)d_in[3];
  const float* Wqu = (const float*)d_in[4];
  const float* Wpv = (const float*)d_in[5];
  const float* Wih = (const float*)d_in[6];
  const float* Whh = (const float*)d_in[7];
  const float* bih = (const float*)d_in[8];
  const float* bhh = (const float*)d_in[9];
  float* out = (float*)d_out;

  char* ws = (char*)d_ws;
  unsigned short* Wh  = (unsigned short*)(ws + 0x000000);  // 1,310,720 B
  unsigned short* Wm  = (unsigned short*)(ws + 0x140000);  // 1,310,720 B
  float*    G0     = (float*)(ws + 0x280000);              //   335,872 B
  float*    G1     = (float*)(ws + 0x2D2000);              //   335,872 B
  float*    WquT   = (float*)(ws + 0x2D2000);              // alias G1 (prep-only)
  unsigned* flags  = (unsigned*)(ws + 0x324000);           //     8,192 B
  float*    qs     = (float*)(ws + 0x326000);              //    65,536 B
  float*    zbv    = (float*)(ws + 0x336000);              //    65,536 B
  unsigned short* KbH = (unsigned short*)(ws + 0x346000);  // 8,388,608 B
  unsigned short* KbM = (unsigned short*)(ws + 0xB46000);  // 8,388,608 B
  if (ws_size < 0x1360000u) return;                        // total used: 0x1346000

  const int prep_items = WCOLS * 256 + 65536 + 2048;       // 722,944
  prep_kernel<<<(prep_items + 255) / 256, 256, 0, stream>>>(
      Wpu, Wqu, Wpv, Wih, Whh, Wh, Wm, WquT, flags);

  prep_qz<<<64, 256, 0, stream>>>(q, WquT, qs, zbv);

  const size_t k_smem = 128 * 257 * sizeof(float);          // 131,584 B
  hipFuncSetAttribute(reinterpret_cast<const void*>(prep_K),
                      hipFuncAttributeMaxDynamicSharedMemorySize, (int)k_smem);
  prep_K<<<256, 256, k_smem, stream>>>(q, WquT, KbH, KbM);

  // 128 WGs = 8 groups x 16 members (256 threads each).
  pq_main<<<NGRP * GWGS, NT, 0, stream>>>(p, bih, bhh, Wh, Wm, KbH, KbM, qs, zbv,
                                          v0, G0, G1, flags, out);
}